// Round 12
// baseline (112.587 us; speedup 1.0000x reference)
//
#include <hip/hip_runtime.h>
#include <math.h>

#define N_NODES 30000
#define N_EDGES 150000
#define NB_E ((N_EDGES + 255) / 256)   // 586 edge-blocks in fused prep
// K = IN*H = 512 hidden units in the edge MLP; 513 piecewise-linear intervals.
// theta(a) = a*A_m + B2_m on interval m. Tables packed: one uint32 per entry,
// hi16 = bf16(A), lo16 = bf16(B2), transposed layout T[m][o*16+i] so lane o
// reads its 32 weights as 4 uint4s. Pipeline: k1z -> {kb1 || p1} ->
// {scan || p3s} -> k3(2 edges/group) -> k4(32 lanes/node) ->
// k56(8 lanes/node).  6 launches.
// NOTE: no hipMemsetAsync — rocclr fill kernel is pathological in-graph.

__device__ __forceinline__ unsigned bf16_rne(float f) {
    unsigned u = __float_as_uint(f);
    u += 0x7FFFu + ((u >> 16) & 1u);
    return u >> 16;
}

// ---------------------------------------------------------------------------
// K1Z: breakpoints t_k = -b1_k/W1_k, O(n^2) rank sort; then zero deg[N].
// 1 block x 512.
// ---------------------------------------------------------------------------
__global__ void k1z_rank(const float* __restrict__ W1, const float* __restrict__ b1,
                         float* __restrict__ tsort, int* __restrict__ ksort,
                         int* __restrict__ deg) {
    __shared__ float st[512];
    int tid = threadIdx.x;
    float w = W1[tid], b = b1[tid];
    float t = (w != 0.0f) ? (-b / w) : 3.0e38f;
    st[tid] = t;
    __syncthreads();
    int rank = 0;
#pragma unroll 8
    for (int j = 0; j < 512; ++j) {
        float tj = st[j];
        rank += (tj < t || (tj == t && j < tid)) ? 1 : 0;
    }
    tsort[rank] = t;
    ksort[rank] = tid;
    // zero deg (vector stores; kernel boundary orders it before f2's atomics)
    int4* dz = (int4*)deg;
    for (int i = tid; i < N_NODES / 4; i += 512) dz[i] = make_int4(0, 0, 0, 0);
}

// ---------------------------------------------------------------------------
// F2: fused independent pair.
// Blocks [0, NB_E): per-edge prep — in-degree atomic (old = rank within dst)
//   + interval m via binary search; rankm[e] = rank<<10 | m.
// Blocks [NB_E, NB_E+64): p1 chunk partial sums (32 chunks x 16 ranks);
//   thread owns storage index jt; W2 column jsrc = (jt&15)*32 + (jt>>4).
// ---------------------------------------------------------------------------
__global__ void __launch_bounds__(256) f2_prep(
        const int* __restrict__ ei, const float* __restrict__ ea,
        const float* __restrict__ tsort,
        int* __restrict__ deg, int* __restrict__ rankm,
        const float* __restrict__ W1, const float* __restrict__ b1,
        const float* __restrict__ W2, const int* __restrict__ ksort,
        float* __restrict__ PbA, float* __restrict__ PbB,
        float* __restrict__ SA, float* __restrict__ SB) {
    if (blockIdx.x < NB_E) {
        __shared__ float ts[512];
        for (int i = threadIdx.x; i < 512; i += 256) ts[i] = tsort[i];
        __syncthreads();
        int e = blockIdx.x * 256 + threadIdx.x;
        if (e >= N_EDGES) return;
        int rank = atomicAdd(&deg[ei[N_EDGES + e]], 1);
        float a = ea[e];
        int lo = 0, hi = 512;
        while (lo < hi) {
            int mid = (lo + hi) >> 1;
            if (ts[mid] < a) lo = mid + 1; else hi = mid;
        }
        rankm[e] = (rank << 10) | lo;
    } else {
        int bb = blockIdx.x - NB_E;
        int c = bb & 31;
        int jc = bb >> 5;
        int jt = jc * 256 + threadIdx.x;
        int jsrc = ((jt & 15) << 5) | (jt >> 4);
        float ba = 0.0f, bb2 = 0.0f, sa = 0.0f, sb = 0.0f;
#pragma unroll 4
        for (int s = 0; s < 16; ++s) {
            int k = c * 16 + s;
            float w = W1[k], b = b1[k];
            bool act = (w < 0.0f) || (w == 0.0f && b > 0.0f);
            if (act) {
                float w2 = W2[k * 512 + jsrc];
                ba = fmaf(w, w2, ba);
                bb2 = fmaf(b, w2, bb2);
            }
            int kr = ksort[c * 16 + s];
            float wr = W1[kr], br = b1[kr];
            float sgn = (wr > 0.0f) ? 1.0f : ((wr < 0.0f) ? -1.0f : 0.0f);
            float w2r = W2[kr * 512 + jsrc];
            sa = fmaf(sgn * wr, w2r, sa);
            sb = fmaf(sgn * br, w2r, sb);
        }
        PbA[c * 512 + jt] = ba; PbB[c * 512 + jt] = bb2;
        SA[c * 512 + jt] = sa;  SB[c * 512 + jt] = sb;
    }
}

// ---------------------------------------------------------------------------
// F3: fused independent pair, 1024 threads/block, grid 17.
// Block 0: exclusive scan of deg[30000] -> offs.
// Blocks 1..16: p3s table emit; c = (blk-1)*2 + (tid>>9), jt = tid&511.
// T[m*512+jt] = bf16(A)<<16 | bf16(B2) (running sums stay f32).
// ---------------------------------------------------------------------------
__global__ void __launch_bounds__(1024) f3_scan_emit(
        const int* __restrict__ deg, int* __restrict__ offs,
        const float* __restrict__ W1, const float* __restrict__ b1,
        const float* __restrict__ b2, const float* __restrict__ W2,
        const int* __restrict__ ksort,
        const float* __restrict__ PbA, const float* __restrict__ PbB,
        const float* __restrict__ SA, const float* __restrict__ SB,
        unsigned int* __restrict__ T) {
    __shared__ int part[1024];
    if (blockIdx.x == 0) {
        int t = threadIdx.x;
        int base = t * 30;
        int loc[30];
        int s = 0;
#pragma unroll
        for (int i = 0; i < 30; ++i) {
            int idx = base + i;
            int v = (idx < N_NODES) ? deg[idx] : 0;
            loc[i] = v;
            s += v;
        }
        part[t] = s;
        __syncthreads();
        for (int off = 1; off < 1024; off <<= 1) {
            int v = part[t];
            int add = (t >= off) ? part[t - off] : 0;
            __syncthreads();
            part[t] = v + add;
            __syncthreads();
        }
        int run = (t > 0) ? part[t - 1] : 0;
#pragma unroll
        for (int i = 0; i < 30; ++i) {
            int idx = base + i;
            if (idx < N_NODES) offs[idx] = run;
            run += loc[i];
        }
        if (t == 1023) offs[N_NODES] = run;
    } else {
        int c = (blockIdx.x - 1) * 2 + (threadIdx.x >> 9);
        int jt = threadIdx.x & 511;
        int jsrc = ((jt & 15) << 5) | (jt >> 4);
        float runA = 0.0f, runB = 0.0f;
#pragma unroll
        for (int c2 = 0; c2 < 32; ++c2) {
            runA += PbA[c2 * 512 + jt];
            runB += PbB[c2 * 512 + jt];
            if (c2 < c) { runA += SA[c2 * 512 + jt]; runB += SB[c2 * 512 + jt]; }
        }
        float bb2 = b2[jsrc];
#pragma unroll 4
        for (int s = 0; s < 16; ++s) {
            int m = c * 16 + s;
            T[m * 512 + jt] = (bf16_rne(runA) << 16) | bf16_rne(runB + bb2);
            int k = ksort[m];
            float w = W1[k], b = b1[k];
            float sgn = (w > 0.0f) ? 1.0f : ((w < 0.0f) ? -1.0f : 0.0f);
            float w2 = W2[k * 512 + jsrc];
            runA = fmaf(sgn * w, w2, runA);
            runB = fmaf(sgn * b, w2, runB);
        }
        if (c == 31) {
            T[512 * 512 + jt] = (bf16_rne(runA) << 16) | bf16_rne(runB + bb2);
        }
    }
}

// ---------------------------------------------------------------------------
// K3: TWO edges per 32-lane group (double memory-level parallelism; k3 is
// L2-latency-bound). Metadata vectorized (float2/int2); 8 independent uint4
// table loads in flight; interleaved FMA chains; bf16 stores to CSR slots;
// lane 0 fills ssrc for both edges.
// ---------------------------------------------------------------------------
__global__ void __launch_bounds__(256) k3_edges(
        const float* __restrict__ x, const float* __restrict__ ea,
        const int* __restrict__ ei, const int* __restrict__ rankm,
        const int* __restrict__ offs, const unsigned int* __restrict__ T,
        unsigned short* __restrict__ msgbuf, int* __restrict__ ssrc) {
    int gid = blockIdx.x * blockDim.x + threadIdx.x;
    int lane = gid & 31;
    int g = gid >> 5;
    int e0 = g << 1;
    if (e0 >= N_EDGES) return;
    float2 aa = *(const float2*)(ea + e0);
    int2 ss = *(const int2*)(ei + e0);
    int2 dd = *(const int2*)(ei + N_EDGES + e0);
    int2 rr = *(const int2*)(rankm + e0);
    int m0 = rr.x & 1023, m1 = rr.y & 1023;
    int slot0 = offs[dd.x] + (rr.x >> 10);
    int slot1 = offs[dd.y] + (rr.y >> 10);
    const uint4* T0 = (const uint4*)(T + m0 * 512 + lane * 16);
    const uint4* T1 = (const uint4*)(T + m1 * 512 + lane * 16);
    uint4 p0 = T0[0], p1 = T0[1], p2 = T0[2], p3 = T0[3];
    uint4 q0 = T1[0], q1 = T1[1], q2 = T1[2], q3 = T1[3];
    float xv0 = (lane < 16) ? x[ss.x * 16 + lane] : 0.0f;
    float xv1 = (lane < 16) ? x[ss.y * 16 + lane] : 0.0f;
    float xa0 = 0.0f, xb0 = 0.0f, xa1 = 0.0f, xb1 = 0.0f;
    float xi;
#define STEP2(w0, w1, i)                                                   \
    xi = __shfl(xv0, i, 32);                                               \
    xa0 = fmaf(xi, __uint_as_float((w0) & 0xFFFF0000u), xa0);              \
    xb0 = fmaf(xi, __uint_as_float((w0) << 16), xb0);                      \
    xi = __shfl(xv1, i, 32);                                               \
    xa1 = fmaf(xi, __uint_as_float((w1) & 0xFFFF0000u), xa1);              \
    xb1 = fmaf(xi, __uint_as_float((w1) << 16), xb1);
    STEP2(p0.x, q0.x, 0)  STEP2(p0.y, q0.y, 1)  STEP2(p0.z, q0.z, 2)  STEP2(p0.w, q0.w, 3)
    STEP2(p1.x, q1.x, 4)  STEP2(p1.y, q1.y, 5)  STEP2(p1.z, q1.z, 6)  STEP2(p1.w, q1.w, 7)
    STEP2(p2.x, q2.x, 8)  STEP2(p2.y, q2.y, 9)  STEP2(p2.z, q2.z, 10) STEP2(p2.w, q2.w, 11)
    STEP2(p3.x, q3.x, 12) STEP2(p3.y, q3.y, 13) STEP2(p3.z, q3.z, 14) STEP2(p3.w, q3.w, 15)
#undef STEP2
    float msg0 = fmaf(aa.x, xa0, xb0);
    float msg1 = fmaf(aa.y, xa1, xb1);
    msgbuf[slot0 * 32 + lane] = (unsigned short)bf16_rne(msg0);
    msgbuf[slot1 * 32 + lane] = (unsigned short)bf16_rne(msg1);
    if (lane == 0) { ssrc[slot0] = ss.x; ssrc[slot1] = ss.y; }
}

// ---------------------------------------------------------------------------
// K4: 32 lanes per node (was 1 thread/node at 118 blocks = half the chip
// idle). Lane o owns output column o: msgbuf row reads are one coalesced
// 64B line per row; x broadcast via shfl; h.Wg contraction via 5-step
// shfl_xor butterfly. 3750 blocks.
// ---------------------------------------------------------------------------
__global__ void __launch_bounds__(256) k4_nodes(
        const float* __restrict__ x, const int* __restrict__ offs,
        const unsigned short* __restrict__ msgbuf,
        const float* __restrict__ root, const float* __restrict__ bias1,
        const float* __restrict__ Wg, float* __restrict__ xw12) {
    __shared__ float sroot[512], sb1[32], swg[320];
    for (int i = threadIdx.x; i < 512; i += blockDim.x) sroot[i] = root[i];
    for (int i = threadIdx.x; i < 32; i += blockDim.x) sb1[i] = bias1[i];
    for (int i = threadIdx.x; i < 320; i += blockDim.x) swg[i] = Wg[i];
    __syncthreads();
    int gid = blockIdx.x * blockDim.x + threadIdx.x;
    int lane = gid & 31;        // output column o
    int n = gid >> 5;           // node
    if (n >= N_NODES) return;
    int s0 = offs[n], s1 = offs[n + 1];
    float agg = 0.0f;
    for (int sl = s0; sl < s1; ++sl) {
        unsigned short v = msgbuf[sl * 32 + lane];
        agg += __uint_as_float(((unsigned)v) << 16);
    }
    float c = (float)(s1 - s0);
    float inv = 1.0f / fmaxf(c, 1.0f);
    float xv = (lane < 16) ? x[n * 16 + lane] : 0.0f;
    float h = fmaf(agg, inv, sb1[lane]);
    float xi;
#pragma unroll
    for (int i = 0; i < 16; ++i) {
        xi = __shfl(xv, i, 32);
        h = fmaf(xi, sroot[i * 32 + lane], h);
    }
    h = fmaxf(h, 0.0f);
    float p[10];
#pragma unroll
    for (int cc = 0; cc < 10; ++cc) p[cc] = h * swg[lane * 10 + cc];
#pragma unroll
    for (int st = 1; st < 32; st <<= 1) {
#pragma unroll
        for (int cc = 0; cc < 10; ++cc) p[cc] += __shfl_xor(p[cc], st, 32);
    }
    float4* op = (float4*)(xw12 + n * 12);
    if (lane == 0) op[0] = make_float4(p[0], p[1], p[2], p[3]);
    else if (lane == 1) op[1] = make_float4(p[4], p[5], p[6], p[7]);
    else if (lane == 2) op[2] = make_float4(p[8], p[9], rsqrtf(c + 1.0f), 0.0f);
}

// ---------------------------------------------------------------------------
// K56: 8 lanes per node. Neighbors round-robin across lanes (self-loop is
// lane 0's extra term); 3-step shfl_xor butterfly; lane 0 does bias +
// log_softmax + writes. 938 blocks.
// ---------------------------------------------------------------------------
__global__ void __launch_bounds__(256) k56_final(
        const int* __restrict__ offs, const int* __restrict__ ssrc,
        const float* __restrict__ xw12, const float* __restrict__ bg,
        float* __restrict__ out) {
    __shared__ float sbg[16];
    if (threadIdx.x < 10) sbg[threadIdx.x] = bg[threadIdx.x];
    __syncthreads();
    int gid = blockIdx.x * blockDim.x + threadIdx.x;
    int lane = gid & 7;
    int n = gid >> 3;
    if (n >= N_NODES) return;
    const float4* base = (const float4*)xw12;
    float dn = xw12[n * 12 + 10];
    float acc[10];
#pragma unroll
    for (int cc = 0; cc < 10; ++cc) acc[cc] = 0.0f;
    if (lane == 0) {
        float4 r0 = base[n * 3], r1 = base[n * 3 + 1], r2 = base[n * 3 + 2];
        float d2 = dn * dn;
        acc[0] = r0.x * d2; acc[1] = r0.y * d2; acc[2] = r0.z * d2;
        acc[3] = r0.w * d2; acc[4] = r1.x * d2; acc[5] = r1.y * d2;
        acc[6] = r1.z * d2; acc[7] = r1.w * d2; acc[8] = r2.x * d2;
        acc[9] = r2.y * d2;
    }
    int s0 = offs[n], s1 = offs[n + 1];
    for (int sl = s0 + lane; sl < s1; sl += 8) {
        int s = ssrc[sl];
        float4 q0 = base[s * 3], q1 = base[s * 3 + 1], q2 = base[s * 3 + 2];
        float nf = q2.z * dn;
        acc[0] = fmaf(q0.x, nf, acc[0]); acc[1] = fmaf(q0.y, nf, acc[1]);
        acc[2] = fmaf(q0.z, nf, acc[2]); acc[3] = fmaf(q0.w, nf, acc[3]);
        acc[4] = fmaf(q1.x, nf, acc[4]); acc[5] = fmaf(q1.y, nf, acc[5]);
        acc[6] = fmaf(q1.z, nf, acc[6]); acc[7] = fmaf(q1.w, nf, acc[7]);
        acc[8] = fmaf(q2.x, nf, acc[8]); acc[9] = fmaf(q2.y, nf, acc[9]);
    }
#pragma unroll
    for (int st = 1; st < 8; st <<= 1) {
#pragma unroll
        for (int cc = 0; cc < 10; ++cc) acc[cc] += __shfl_xor(acc[cc], st, 8);
    }
    if (lane == 0) {
        float mx = -1e30f;
#pragma unroll
        for (int cc = 0; cc < 10; ++cc) { acc[cc] += sbg[cc]; mx = fmaxf(mx, acc[cc]); }
        float se = 0.0f;
#pragma unroll
        for (int cc = 0; cc < 10; ++cc) se += expf(acc[cc] - mx);
        float lse = logf(se) + mx;
        float2* o2 = (float2*)(out + n * 10);
        o2[0] = make_float2(acc[0] - lse, acc[1] - lse);
        o2[1] = make_float2(acc[2] - lse, acc[3] - lse);
        o2[2] = make_float2(acc[4] - lse, acc[5] - lse);
        o2[3] = make_float2(acc[6] - lse, acc[7] - lse);
        o2[4] = make_float2(acc[8] - lse, acc[9] - lse);
    }
}

// ---------------------------------------------------------------------------
extern "C" void kernel_launch(void* const* d_in, const int* in_sizes, int n_in,
                              void* d_out, int out_size, void* d_ws, size_t ws_size,
                              hipStream_t stream) {
    const float* x     = (const float*)d_in[0];
    const float* ea    = (const float*)d_in[1];
    const float* W1    = (const float*)d_in[2];
    const float* b1    = (const float*)d_in[3];
    const float* W2    = (const float*)d_in[4];
    const float* b2    = (const float*)d_in[5];
    const float* root  = (const float*)d_in[6];
    const float* bias1 = (const float*)d_in[7];
    const float* Wg    = (const float*)d_in[8];
    const float* bg    = (const float*)d_in[9];
    const int*   ei    = (const int*)d_in[10];
    float* out = (float*)d_out;

    // workspace layout (4-byte units; 16B-aligned segments)
    unsigned int* T = (unsigned int*)d_ws;            // 513*512 packed bf16x2
    float* tsort  = (float*)(T + 513 * 512);          // 512
    int*   ksort  = (int*)(tsort + 512);              // 512
    unsigned short* msgbuf = (unsigned short*)(ksort + 512); // E*32 bf16 (2.4M units)
    int*   deg    = (int*)((float*)msgbuf + 2400000); // N  <- zeroed in k1z
    int*   offs   = deg + N_NODES;                    // N+4
    int*   rankm  = offs + N_NODES + 4;               // E
    int*   ssrc   = rankm + N_EDGES;                  // E
    float* xw12   = (float*)(ssrc + N_EDGES);         // N*12 (16B aligned)
    float* PbA    = xw12 + N_NODES * 12;              // 32*512
    float* PbB    = PbA + 32 * 512;
    float* SA     = PbB + 32 * 512;
    float* SB     = SA + 32 * 512;

    k1z_rank<<<1, 512, 0, stream>>>(W1, b1, tsort, ksort, deg);
    f2_prep<<<NB_E + 64, 256, 0, stream>>>(ei, ea, tsort, deg, rankm,
                                           W1, b1, W2, ksort, PbA, PbB, SA, SB);
    f3_scan_emit<<<17, 1024, 0, stream>>>(deg, offs, W1, b1, b2, W2, ksort,
                                          PbA, PbB, SA, SB, T);
    k3_edges<<<(N_EDGES / 2 * 32 + 255) / 256, 256, 0, stream>>>(
        x, ea, ei, rankm, offs, T, msgbuf, ssrc);
    k4_nodes<<<(N_NODES * 32 + 255) / 256, 256, 0, stream>>>(
        x, offs, msgbuf, root, bias1, Wg, xw12);
    k56_final<<<(N_NODES * 8 + 255) / 256, 256, 0, stream>>>(offs, ssrc, xw12,
                                                             bg, out);
}

// Round 13
// 105.198 us; speedup vs baseline: 1.0702x; 1.0702x over previous
//
#include <hip/hip_runtime.h>
#include <math.h>

#define N_NODES 30000
#define N_EDGES 150000
#define NB_E ((N_EDGES + 255) / 256)   // 586 edge-blocks in fused prep
// K = IN*H = 512 hidden units in the edge MLP; 513 piecewise-linear intervals.
// theta(a) = a*A_m + B2_m on interval m. Tables packed: one uint32 per entry,
// hi16 = bf16(A), lo16 = bf16(B2), transposed layout T[m][o*16+i] so lane o
// reads its 32 weights as 4 uint4s. Pipeline: k1z(sort || zero) ->
// {kb1 || p1} -> {scan || p3s} -> k3(2 edges/group, f32 atomic into summed)
// -> k4(scalar/node) -> k56(scalar/node).  6 launches.
// R12 lesson: wave-parallel k4/k56 regressed (shfl overhead > occupancy win);
// scalar forms measured faster. R7 lesson: f32 atomics == plain stores here.
// NOTE: no hipMemsetAsync — rocclr fill kernel is pathological in-graph.

__device__ __forceinline__ unsigned bf16_rne(float f) {
    unsigned u = __float_as_uint(f);
    u += 0x7FFFu + ((u >> 16) & 1u);
    return u >> 16;
}

// ---------------------------------------------------------------------------
// K1Z: block 0: breakpoints t_k = -b1_k/W1_k + O(n^2) rank sort.
// Blocks 1..31: zero summed[N*32] + deg[N] (contiguous, N*33 ints).
// ---------------------------------------------------------------------------
__global__ void k1z_rank(const float* __restrict__ W1, const float* __restrict__ b1,
                         float* __restrict__ tsort, int* __restrict__ ksort,
                         int* __restrict__ zbase /* summed..deg, N*33 ints */) {
    if (blockIdx.x == 0) {
        __shared__ float st[512];
        int tid = threadIdx.x;
        float w = W1[tid], b = b1[tid];
        float t = (w != 0.0f) ? (-b / w) : 3.0e38f;
        st[tid] = t;
        __syncthreads();
        int rank = 0;
#pragma unroll 8
        for (int j = 0; j < 512; ++j) {
            float tj = st[j];
            rank += (tj < t || (tj == t && j < tid)) ? 1 : 0;
        }
        tsort[rank] = t;
        ksort[rank] = tid;
    } else {
        int4* dz = (int4*)zbase;
        const int n4 = N_NODES * 33 / 4;   // 247500
        int4 z = make_int4(0, 0, 0, 0);
        for (int i = (blockIdx.x - 1) * 512 + threadIdx.x; i < n4; i += 31 * 512)
            dz[i] = z;
    }
}

// ---------------------------------------------------------------------------
// F2: fused independent pair.
// Blocks [0, NB_E): per-edge prep — in-degree atomic (old = rank within dst)
//   + interval m via binary search; rankm[e] = rank<<10 | m.
// Blocks [NB_E, NB_E+64): p1 chunk partial sums (32 chunks x 16 ranks);
//   thread owns storage index jt; W2 column jsrc = (jt&15)*32 + (jt>>4).
// ---------------------------------------------------------------------------
__global__ void __launch_bounds__(256) f2_prep(
        const int* __restrict__ ei, const float* __restrict__ ea,
        const float* __restrict__ tsort,
        int* __restrict__ deg, int* __restrict__ rankm,
        const float* __restrict__ W1, const float* __restrict__ b1,
        const float* __restrict__ W2, const int* __restrict__ ksort,
        float* __restrict__ PbA, float* __restrict__ PbB,
        float* __restrict__ SA, float* __restrict__ SB) {
    if (blockIdx.x < NB_E) {
        __shared__ float ts[512];
        for (int i = threadIdx.x; i < 512; i += 256) ts[i] = tsort[i];
        __syncthreads();
        int e = blockIdx.x * 256 + threadIdx.x;
        if (e >= N_EDGES) return;
        int rank = atomicAdd(&deg[ei[N_EDGES + e]], 1);
        float a = ea[e];
        int lo = 0, hi = 512;
        while (lo < hi) {
            int mid = (lo + hi) >> 1;
            if (ts[mid] < a) lo = mid + 1; else hi = mid;
        }
        rankm[e] = (rank << 10) | lo;
    } else {
        int bb = blockIdx.x - NB_E;
        int c = bb & 31;
        int jc = bb >> 5;
        int jt = jc * 256 + threadIdx.x;
        int jsrc = ((jt & 15) << 5) | (jt >> 4);
        float ba = 0.0f, bb2 = 0.0f, sa = 0.0f, sb = 0.0f;
#pragma unroll 4
        for (int s = 0; s < 16; ++s) {
            int k = c * 16 + s;
            float w = W1[k], b = b1[k];
            bool act = (w < 0.0f) || (w == 0.0f && b > 0.0f);
            if (act) {
                float w2 = W2[k * 512 + jsrc];
                ba = fmaf(w, w2, ba);
                bb2 = fmaf(b, w2, bb2);
            }
            int kr = ksort[c * 16 + s];
            float wr = W1[kr], br = b1[kr];
            float sgn = (wr > 0.0f) ? 1.0f : ((wr < 0.0f) ? -1.0f : 0.0f);
            float w2r = W2[kr * 512 + jsrc];
            sa = fmaf(sgn * wr, w2r, sa);
            sb = fmaf(sgn * br, w2r, sb);
        }
        PbA[c * 512 + jt] = ba; PbB[c * 512 + jt] = bb2;
        SA[c * 512 + jt] = sa;  SB[c * 512 + jt] = sb;
    }
}

// ---------------------------------------------------------------------------
// F3: fused independent pair, 1024 threads/block, grid 17.
// Block 0: exclusive scan of deg[30000] -> offs.
// Blocks 1..16: p3s table emit; c = (blk-1)*2 + (tid>>9), jt = tid&511.
// T[m*512+jt] = bf16(A)<<16 | bf16(B2) (running sums stay f32).
// ---------------------------------------------------------------------------
__global__ void __launch_bounds__(1024) f3_scan_emit(
        const int* __restrict__ deg, int* __restrict__ offs,
        const float* __restrict__ W1, const float* __restrict__ b1,
        const float* __restrict__ b2, const float* __restrict__ W2,
        const int* __restrict__ ksort,
        const float* __restrict__ PbA, const float* __restrict__ PbB,
        const float* __restrict__ SA, const float* __restrict__ SB,
        unsigned int* __restrict__ T) {
    __shared__ int part[1024];
    if (blockIdx.x == 0) {
        int t = threadIdx.x;
        int base = t * 30;
        int loc[30];
        int s = 0;
#pragma unroll
        for (int i = 0; i < 30; ++i) {
            int idx = base + i;
            int v = (idx < N_NODES) ? deg[idx] : 0;
            loc[i] = v;
            s += v;
        }
        part[t] = s;
        __syncthreads();
        for (int off = 1; off < 1024; off <<= 1) {
            int v = part[t];
            int add = (t >= off) ? part[t - off] : 0;
            __syncthreads();
            part[t] = v + add;
            __syncthreads();
        }
        int run = (t > 0) ? part[t - 1] : 0;
#pragma unroll
        for (int i = 0; i < 30; ++i) {
            int idx = base + i;
            if (idx < N_NODES) offs[idx] = run;
            run += loc[i];
        }
        if (t == 1023) offs[N_NODES] = run;
    } else {
        int c = (blockIdx.x - 1) * 2 + (threadIdx.x >> 9);
        int jt = threadIdx.x & 511;
        int jsrc = ((jt & 15) << 5) | (jt >> 4);
        float runA = 0.0f, runB = 0.0f;
#pragma unroll
        for (int c2 = 0; c2 < 32; ++c2) {
            runA += PbA[c2 * 512 + jt];
            runB += PbB[c2 * 512 + jt];
            if (c2 < c) { runA += SA[c2 * 512 + jt]; runB += SB[c2 * 512 + jt]; }
        }
        float bb2 = b2[jsrc];
#pragma unroll 4
        for (int s = 0; s < 16; ++s) {
            int m = c * 16 + s;
            T[m * 512 + jt] = (bf16_rne(runA) << 16) | bf16_rne(runB + bb2);
            int k = ksort[m];
            float w = W1[k], b = b1[k];
            float sgn = (w > 0.0f) ? 1.0f : ((w < 0.0f) ? -1.0f : 0.0f);
            float w2 = W2[k * 512 + jsrc];
            runA = fmaf(sgn * w, w2, runA);
            runB = fmaf(sgn * b, w2, runB);
        }
        if (c == 31) {
            T[512 * 512 + jt] = (bf16_rne(runA) << 16) | bf16_rne(runB + bb2);
        }
    }
}

// ---------------------------------------------------------------------------
// K3: TWO edges per 32-lane group (memory-level parallelism; k3 is
// L2-latency/BW-bound). f32 atomicAdd of the message directly into
// summed[dst*32+lane] (R7 proved atomic == store here; kills msgbuf
// round-trip). lane 0 fills ssrc CSR slots (offs[d]+rank, atomic-free).
// ---------------------------------------------------------------------------
__global__ void __launch_bounds__(256) k3_edges(
        const float* __restrict__ x, const float* __restrict__ ea,
        const int* __restrict__ ei, const int* __restrict__ rankm,
        const int* __restrict__ offs, const unsigned int* __restrict__ T,
        float* __restrict__ summed, int* __restrict__ ssrc) {
    int gid = blockIdx.x * blockDim.x + threadIdx.x;
    int lane = gid & 31;
    int g = gid >> 5;
    int e0 = g << 1;
    if (e0 >= N_EDGES) return;
    float2 aa = *(const float2*)(ea + e0);
    int2 ss = *(const int2*)(ei + e0);
    int2 dd = *(const int2*)(ei + N_EDGES + e0);
    int2 rr = *(const int2*)(rankm + e0);
    int m0 = rr.x & 1023, m1 = rr.y & 1023;
    const uint4* T0 = (const uint4*)(T + m0 * 512 + lane * 16);
    const uint4* T1 = (const uint4*)(T + m1 * 512 + lane * 16);
    uint4 p0 = T0[0], p1 = T0[1], p2 = T0[2], p3 = T0[3];
    uint4 q0 = T1[0], q1 = T1[1], q2 = T1[2], q3 = T1[3];
    float xv0 = (lane < 16) ? x[ss.x * 16 + lane] : 0.0f;
    float xv1 = (lane < 16) ? x[ss.y * 16 + lane] : 0.0f;
    float xa0 = 0.0f, xb0 = 0.0f, xa1 = 0.0f, xb1 = 0.0f;
    float xi;
#define STEP2(w0, w1, i)                                                   \
    xi = __shfl(xv0, i, 32);                                               \
    xa0 = fmaf(xi, __uint_as_float((w0) & 0xFFFF0000u), xa0);              \
    xb0 = fmaf(xi, __uint_as_float((w0) << 16), xb0);                      \
    xi = __shfl(xv1, i, 32);                                               \
    xa1 = fmaf(xi, __uint_as_float((w1) & 0xFFFF0000u), xa1);              \
    xb1 = fmaf(xi, __uint_as_float((w1) << 16), xb1);
    STEP2(p0.x, q0.x, 0)  STEP2(p0.y, q0.y, 1)  STEP2(p0.z, q0.z, 2)  STEP2(p0.w, q0.w, 3)
    STEP2(p1.x, q1.x, 4)  STEP2(p1.y, q1.y, 5)  STEP2(p1.z, q1.z, 6)  STEP2(p1.w, q1.w, 7)
    STEP2(p2.x, q2.x, 8)  STEP2(p2.y, q2.y, 9)  STEP2(p2.z, q2.z, 10) STEP2(p2.w, q2.w, 11)
    STEP2(p3.x, q3.x, 12) STEP2(p3.y, q3.y, 13) STEP2(p3.z, q3.z, 14) STEP2(p3.w, q3.w, 15)
#undef STEP2
    float msg0 = fmaf(aa.x, xa0, xb0);
    float msg1 = fmaf(aa.y, xa1, xb1);
    atomicAdd(&summed[dd.x * 32 + lane], msg0);
    atomicAdd(&summed[dd.y * 32 + lane], msg1);
    if (lane == 0) {
        ssrc[offs[dd.x] + (rr.x >> 10)] = ss.x;
        ssrc[offs[dd.y] + (rr.y >> 10)] = ss.y;
    }
}

// ---------------------------------------------------------------------------
// K4: scalar per node (R5 form — measured best): aggr = summed/max(cnt,1)
// via 8 float4 coalesced reads; h1 = relu(aggr + x@root + bias1);
// xw12[0..9] = h1@Wg; [10] = rsqrt(deg+1); [11] = 0.
// ---------------------------------------------------------------------------
__global__ void k4_nodes(const float* __restrict__ x, const int* __restrict__ offs,
                         const float* __restrict__ summed,
                         const float* __restrict__ root, const float* __restrict__ bias1,
                         const float* __restrict__ Wg,
                         float* __restrict__ xw12) {
    __shared__ float sroot[512], sb1[32], swg[320];
    for (int i = threadIdx.x; i < 512; i += blockDim.x) sroot[i] = root[i];
    for (int i = threadIdx.x; i < 32; i += blockDim.x) sb1[i] = bias1[i];
    for (int i = threadIdx.x; i < 320; i += blockDim.x) swg[i] = Wg[i];
    __syncthreads();
    int n = blockIdx.x * blockDim.x + threadIdx.x;
    if (n >= N_NODES) return;
    float c = (float)(offs[n + 1] - offs[n]);
    float inv = 1.0f / fmaxf(c, 1.0f);
    const float4* xp = (const float4*)(x + n * 16);
    float xr[16];
#pragma unroll
    for (int q = 0; q < 4; ++q) {
        float4 v = xp[q];
        xr[q * 4 + 0] = v.x; xr[q * 4 + 1] = v.y;
        xr[q * 4 + 2] = v.z; xr[q * 4 + 3] = v.w;
    }
    const float4* sp = (const float4*)(summed + n * 32);
    float sm[32];
#pragma unroll
    for (int q = 0; q < 8; ++q) {
        float4 v = sp[q];
        sm[q * 4 + 0] = v.x; sm[q * 4 + 1] = v.y;
        sm[q * 4 + 2] = v.z; sm[q * 4 + 3] = v.w;
    }
    float acc[10];
#pragma unroll
    for (int cc = 0; cc < 10; ++cc) acc[cc] = 0.0f;
#pragma unroll
    for (int o = 0; o < 32; ++o) {
        float h = sm[o] * inv + sb1[o];
#pragma unroll
        for (int i = 0; i < 16; ++i) h = fmaf(xr[i], sroot[i * 32 + o], h);
        h = fmaxf(h, 0.0f);
#pragma unroll
        for (int cc = 0; cc < 10; ++cc) acc[cc] = fmaf(h, swg[o * 10 + cc], acc[cc]);
    }
    float4* op = (float4*)(xw12 + n * 12);
    op[0] = make_float4(acc[0], acc[1], acc[2], acc[3]);
    op[1] = make_float4(acc[4], acc[5], acc[6], acc[7]);
    op[2] = make_float4(acc[8], acc[9], rsqrtf(c + 1.0f), 0.0f);
}

// ---------------------------------------------------------------------------
// K56: scalar per node (R11 form — measured best): fused GCN gather +
// self-loop + bias + log_softmax -> d_out. Per neighbor: 3 float4 loads.
// ---------------------------------------------------------------------------
__global__ void k56_final(const int* __restrict__ offs, const int* __restrict__ ssrc,
                          const float* __restrict__ xw12,
                          const float* __restrict__ bg, float* __restrict__ out) {
    __shared__ float sbg[16];
    if (threadIdx.x < 10) sbg[threadIdx.x] = bg[threadIdx.x];
    __syncthreads();
    int n = blockIdx.x * blockDim.x + threadIdx.x;
    if (n >= N_NODES) return;
    const float4* base = (const float4*)xw12;
    float4 r0 = base[n * 3], r1 = base[n * 3 + 1], r2 = base[n * 3 + 2];
    float dn = r2.z;
    float d2 = dn * dn;
    float acc[10];
    acc[0] = fmaf(r0.x, d2, sbg[0]); acc[1] = fmaf(r0.y, d2, sbg[1]);
    acc[2] = fmaf(r0.z, d2, sbg[2]); acc[3] = fmaf(r0.w, d2, sbg[3]);
    acc[4] = fmaf(r1.x, d2, sbg[4]); acc[5] = fmaf(r1.y, d2, sbg[5]);
    acc[6] = fmaf(r1.z, d2, sbg[6]); acc[7] = fmaf(r1.w, d2, sbg[7]);
    acc[8] = fmaf(r2.x, d2, sbg[8]); acc[9] = fmaf(r2.y, d2, sbg[9]);
    int s0 = offs[n], s1 = offs[n + 1];
    for (int sl = s0; sl < s1; ++sl) {
        int s = ssrc[sl];
        float4 q0 = base[s * 3], q1 = base[s * 3 + 1], q2 = base[s * 3 + 2];
        float nf = q2.z * dn;
        acc[0] = fmaf(q0.x, nf, acc[0]); acc[1] = fmaf(q0.y, nf, acc[1]);
        acc[2] = fmaf(q0.z, nf, acc[2]); acc[3] = fmaf(q0.w, nf, acc[3]);
        acc[4] = fmaf(q1.x, nf, acc[4]); acc[5] = fmaf(q1.y, nf, acc[5]);
        acc[6] = fmaf(q1.z, nf, acc[6]); acc[7] = fmaf(q1.w, nf, acc[7]);
        acc[8] = fmaf(q2.x, nf, acc[8]); acc[9] = fmaf(q2.y, nf, acc[9]);
    }
    float mx = -1e30f;
#pragma unroll
    for (int c = 0; c < 10; ++c) mx = fmaxf(mx, acc[c]);
    float se = 0.0f;
#pragma unroll
    for (int c = 0; c < 10; ++c) se += expf(acc[c] - mx);
    float lse = logf(se) + mx;
#pragma unroll
    for (int c = 0; c < 10; ++c) out[n * 10 + c] = acc[c] - lse;
}

// ---------------------------------------------------------------------------
extern "C" void kernel_launch(void* const* d_in, const int* in_sizes, int n_in,
                              void* d_out, int out_size, void* d_ws, size_t ws_size,
                              hipStream_t stream) {
    const float* x     = (const float*)d_in[0];
    const float* ea    = (const float*)d_in[1];
    const float* W1    = (const float*)d_in[2];
    const float* b1    = (const float*)d_in[3];
    const float* W2    = (const float*)d_in[4];
    const float* b2    = (const float*)d_in[5];
    const float* root  = (const float*)d_in[6];
    const float* bias1 = (const float*)d_in[7];
    const float* Wg    = (const float*)d_in[8];
    const float* bg    = (const float*)d_in[9];
    const int*   ei    = (const int*)d_in[10];
    float* out = (float*)d_out;

    // workspace layout (4-byte units; 16B-aligned segments)
    unsigned int* T = (unsigned int*)d_ws;            // 513*512 packed bf16x2
    float* tsort  = (float*)(T + 513 * 512);          // 512
    int*   ksort  = (int*)(tsort + 512);              // 512
    float* summed = (float*)(ksort + 512);            // N*32  <- zeroed in k1z
    int*   deg    = (int*)(summed + N_NODES * 32);    // N     <- zeroed in k1z
    int*   offs   = deg + N_NODES;                    // N+4
    int*   rankm  = offs + N_NODES + 4;               // E
    int*   ssrc   = rankm + N_EDGES;                  // E
    float* xw12   = (float*)(ssrc + N_EDGES);         // N*12 (16B aligned)
    float* PbA    = xw12 + N_NODES * 12;              // 32*512
    float* PbB    = PbA + 32 * 512;
    float* SA     = PbB + 32 * 512;
    float* SB     = SA + 32 * 512;

    k1z_rank<<<32, 512, 0, stream>>>(W1, b1, tsort, ksort, (int*)summed);
    f2_prep<<<NB_E + 64, 256, 0, stream>>>(ei, ea, tsort, deg, rankm,
                                           W1, b1, W2, ksort, PbA, PbB, SA, SB);
    f3_scan_emit<<<17, 1024, 0, stream>>>(deg, offs, W1, b1, b2, W2, ksort,
                                          PbA, PbB, SA, SB, T);
    k3_edges<<<(N_EDGES / 2 * 32 + 255) / 256, 256, 0, stream>>>(
        x, ea, ei, rankm, offs, T, summed, ssrc);
    k4_nodes<<<(N_NODES + 255) / 256, 256, 0, stream>>>(x, offs, summed,
                                                        root, bias1, Wg, xw12);
    k56_final<<<(N_NODES + 255) / 256, 256, 0, stream>>>(offs, ssrc, xw12, bg, out);
}